// Round 3
// baseline (653.431 us; speedup 1.0000x reference)
//
#include <hip/hip_runtime.h>
#include <hip/hip_bf16.h>

#define DEV_INLINE __device__ __forceinline__

constexpr int kN   = 50000;
constexpr int kNT  = 300000;
constexpr int kR   = 64;
constexpr int kRP  = 16;
constexpr int kE   = 32;
constexpr int kC   = 32;
constexpr int kLW  = 64;
constexpr int kNRP = kN * kRP;     // 800000
constexpr int kChunks = (kN + 255) / 256;   // 196

typedef __attribute__((ext_vector_type(8))) short s8v;    // 8 bf16 (4 VGPRs)
typedef __attribute__((ext_vector_type(4))) float f32x4;  // MFMA acc

DEV_INLINE short f2bf(float f) {   // fp32 -> bf16 bits, RNE
  union { float f; unsigned u; } v; v.f = f;
  unsigned r = (v.u + 0x7fffu + ((v.u >> 16) & 1u)) >> 16;
  return (short)r;
}
DEV_INLINE float bf2f(short s) {
  union { unsigned u; float f; } v; v.u = ((unsigned)(unsigned short)s) << 16;
  return v.f;
}
DEV_INLINE float bflo(unsigned u) { union { unsigned x; float f; } a; a.x = u << 16;        return a.f; }
DEV_INLINE float bfhi(unsigned u) { union { unsigned x; float f; } a; a.x = u & 0xffff0000u; return a.f; }

union U4S8 { uint4 u; s8v s; };

// split 8 fp32 -> hi (truncated bf16) + lo (exact residual, truncated bf16)
DEV_INLINE void split8(const float4 A, const float4 B, s8v& hi, s8v& lo) {
  const float f[8] = {A.x, A.y, A.z, A.w, B.x, B.y, B.z, B.w};
  unsigned u[8], l[8];
#pragma unroll
  for (int i = 0; i < 8; i++) { union { float f; unsigned u; } c; c.f = f[i]; u[i] = c.u; }
#pragma unroll
  for (int i = 0; i < 8; i++) {
    union { unsigned u; float f; } t; t.u = u[i] & 0xffff0000u;
    union { float f; unsigned u; } c; c.f = f[i] - t.f; l[i] = c.u;
  }
  U4S8 H, L;
  H.u.x = (u[1] & 0xffff0000u) | (u[0] >> 16);
  H.u.y = (u[3] & 0xffff0000u) | (u[2] >> 16);
  H.u.z = (u[5] & 0xffff0000u) | (u[4] >> 16);
  H.u.w = (u[7] & 0xffff0000u) | (u[6] >> 16);
  L.u.x = (l[1] & 0xffff0000u) | (l[0] >> 16);
  L.u.y = (l[3] & 0xffff0000u) | (l[2] >> 16);
  L.u.z = (l[5] & 0xffff0000u) | (l[4] >> 16);
  L.u.w = (l[7] & 0xffff0000u) | (l[6] >> 16);
  hi = H.s; lo = L.s;
}

// ---------- K0: degree counts for both CSRs ----------
__global__ void __launch_bounds__(256)
k_count(const int* __restrict__ s_idx, const int* __restrict__ o_idx,
        int* __restrict__ cnt_s, int* __restrict__ cnt_o) {
  const int e = blockIdx.x * 256 + threadIdx.x;
  if (e < kNT) {
    atomicAdd(&cnt_s[s_idx[e]], 1);
    atomicAdd(&cnt_o[o_idx[e]], 1);
  }
}

// ---------- parallel scan, phase 1 ----------
__global__ void __launch_bounds__(256)
k_scan_p1(const int* __restrict__ cnt_s, const int* __restrict__ cnt_o,
          int* __restrict__ rp_s, int* __restrict__ rp_o,
          int* __restrict__ bs_s, int* __restrict__ bs_o) {
  const int b = blockIdx.x;
  const bool iso = b >= kChunks;
  const int chunk = iso ? b - kChunks : b;
  const int* cnt = iso ? cnt_o : cnt_s;
  int* rp = iso ? rp_o : rp_s;
  int* bs = iso ? bs_o : bs_s;
  __shared__ int ws[4];
  const int tid = threadIdx.x, wave = tid >> 6, lane = tid & 63;
  const int i = chunk * 256 + tid;
  int v = (i < kN) ? cnt[i] : 0;
  int incl = v;
#pragma unroll
  for (int off = 1; off < 64; off <<= 1) {
    int tmp = __shfl_up(incl, off, 64);
    if (lane >= off) incl += tmp;
  }
  if (lane == 63) ws[wave] = incl;
  __syncthreads();
  int add = 0;
#pragma unroll
  for (int w = 0; w < 4; w++) if (w < wave) add += ws[w];
  incl += add;
  if (i < kN) rp[i + 1] = incl;
  if (tid == 255) bs[chunk] = incl;
}

// ---------- phase 2 ----------
__global__ void __launch_bounds__(256)
k_scan_p2(int* __restrict__ bs_s, int* __restrict__ bs_o) {
  __shared__ int ws[4];
  const int tid = threadIdx.x, wave = tid >> 6, lane = tid & 63;
#pragma unroll 1
  for (int a = 0; a < 2; a++) {
    int* bs = a ? bs_o : bs_s;
    const int v = (tid < kChunks) ? bs[tid] : 0;
    int incl = v;
#pragma unroll
    for (int off = 1; off < 64; off <<= 1) {
      int tmp = __shfl_up(incl, off, 64);
      if (lane >= off) incl += tmp;
    }
    if (lane == 63) ws[wave] = incl;
    __syncthreads();
    int add = 0;
#pragma unroll
    for (int w = 0; w < 4; w++) if (w < wave) add += ws[w];
    incl += add;
    __syncthreads();
    if (tid < kChunks) bs[tid] = incl - v;
    __syncthreads();
  }
}

// ---------- phase 3 ----------
__global__ void __launch_bounds__(256)
k_scan_p3(const int* __restrict__ bs_s, const int* __restrict__ bs_o,
          int* __restrict__ rp_s, int* __restrict__ rp_o) {
  const int b = blockIdx.x;
  const bool iso = b >= kChunks;
  const int chunk = iso ? b - kChunks : b;
  int* rp = iso ? rp_o : rp_s;
  const int* bs = iso ? bs_o : bs_s;
  const int i = chunk * 256 + threadIdx.x;
  if (i < kN) rp[i + 1] += bs[chunk];
  if (chunk == 0 && threadIdx.x == 0) rp[0] = 0;
}

// ---------- scatter edge ids into both CSRs ----------
__global__ void __launch_bounds__(256)
k_scatter2(const int* __restrict__ s_idx, const int* __restrict__ o_idx,
           const int* __restrict__ rowptr_s, int* __restrict__ cursor_s,
           const int* __restrict__ rowptr_o, int* __restrict__ cursor_o,
           int2* __restrict__ eo_s, int* __restrict__ e_o) {
  const int e = blockIdx.x * 256 + threadIdx.x;
  if (e < kNT) {
    const int s = s_idx[e], o = o_idx[e];
    const int ps = atomicAdd(&cursor_s[s], 1);
    int2 v; v.x = e; v.y = o;
    eo_s[rowptr_s[s] + ps] = v;
    const int po = atomicAdd(&cursor_o[o], 1);
    e_o[rowptr_o[o] + po] = e;
  }
}

// ---------- W-frag prep: split-bf16 fragments in B-layout, once ----------
// Layout (shorts): BaH[8192] | BaL[8192] | BbH[2048] | BbL[2048]
// Ba idx: ((mlp*4+nt)*2+ks)*512 + lane*8 + j ; Bb idx: (mlp*2+ks)*512 + lane*8 + j
__global__ void __launch_bounds__(256)
k_wprep(const float* __restrict__ W1a, const float* __restrict__ W1b,
        const float* __restrict__ W2a, const float* __restrict__ W2b,
        short* __restrict__ Wf) {
  const int tid = threadIdx.x;
  for (int i = tid; i < 8192; i += 256) {
    const int j = i & 7, lane = (i >> 3) & 63, ks = (i >> 9) & 1,
              nt = (i >> 10) & 3, mlp = i >> 12;
    const int p = lane & 15, q8 = (lane >> 4) * 8;
    const float* Wa = mlp ? W2a : W1a;
    const float v = Wa[(ks * 32 + q8 + j) * kLW + nt * 16 + p];
    union { float f; unsigned u; } c; c.f = v;
    const short h = (short)(c.u >> 16);
    Wf[i] = h;
    Wf[8192 + i] = f2bf(v - bf2f(h));
  }
  for (int i = tid; i < 2048; i += 256) {
    const int j = i & 7, lane = (i >> 3) & 63, ks = (i >> 9) & 1, mlp = i >> 10;
    const int p = lane & 15, q8 = (lane >> 4) * 8;
    const float* Wb = mlp ? W2b : W1b;
    const float v = Wb[(ks * 32 + q8 + j) * kRP + p];
    union { float f; unsigned u; } c; c.f = v;
    const short h = (short)(c.u >> 16);
    Wf[16384 + i] = h;
    Wf[18432 + i] = f2bf(v - bf2f(h));
  }
}

// ---------- K1: BOTH edge MLPs + softmax via split-bf16 MFMA ----------
// Round-1 structure (mlp-outer, 2 slots/wave — measured 77 µs): B-fragments
// amortize over 64 edges; A re-split per mlp pass is cheap (latency-bound
// kernel, VALU headroom). FUSED per-node partials via atomics.
// Layouts [m89/m91/m118]: A[m=lane&15][k=(lane>>4)*8+j],
// B[k=(lane>>4)*8+j][n=lane&15], C/D col=lane&15, row=(lane>>4)*4+reg.
__global__ void __launch_bounds__(256)
k_lat(const float* __restrict__ nhots, const short* __restrict__ Wf,
      const float* __restrict__ b1a, const float* __restrict__ b1b,
      const float* __restrict__ b2a, const float* __restrict__ b2b,
      const int* __restrict__ s_idx, const int* __restrict__ o_idx,
      float* __restrict__ lat1o, float* __restrict__ lat2o,
      float* __restrict__ C1, float* __restrict__ R2) {
  __shared__ float sHf[4][16][68];       // 17.4 KB, per-wave tile (stride 68: 16B-aligned, 2-way free)
  const int tid = threadIdx.x;
  const int wave = tid >> 6, lane = tid & 63;
  const int p = lane & 15, q = lane >> 4, q8 = (lane >> 4) * 8;

  const uint4* BaH4 = (const uint4*)(Wf);
  const uint4* BaL4 = (const uint4*)(Wf + 8192);
  const uint4* BbH4 = (const uint4*)(Wf + 16384);
  const uint4* BbL4 = (const uint4*)(Wf + 18432);

  const int w2 = (blockIdx.x * 4 + wave) * 2;   // first of 2 tile slots

#pragma unroll 1
  for (int mlp = 0; mlp < 2; mlp++) {
    s8v Bh[4][2], Bl[4][2], Bbh[2], Bbl[2];
#pragma unroll
    for (int nt = 0; nt < 4; nt++)
#pragma unroll
      for (int ks = 0; ks < 2; ks++) {
        U4S8 a, b;
        a.u = BaH4[((mlp * 4 + nt) * 2 + ks) * 64 + lane];
        b.u = BaL4[((mlp * 4 + nt) * 2 + ks) * 64 + lane];
        Bh[nt][ks] = a.s; Bl[nt][ks] = b.s;
      }
#pragma unroll
    for (int ks = 0; ks < 2; ks++) {
      U4S8 a, b;
      a.u = BbH4[(mlp * 2 + ks) * 64 + lane];
      b.u = BbL4[(mlp * 2 + ks) * 64 + lane];
      Bbh[ks] = a.s; Bbl[ks] = b.s;
    }
    const float* bA = mlp ? b2a : b1a;
    const float* bB = mlp ? b2b : b1b;
    float bav[4];
#pragma unroll
    for (int nt = 0; nt < 4; nt++) bav[nt] = bA[nt * 16 + p];
    const float bbv = bB[p];
    float* lato = mlp ? lat2o : lat1o;
    const int* nidx = mlp ? s_idx : o_idx;   // lat2 -> R2[s], lat1 -> C1[o]
    float* part = mlp ? R2 : C1;

#pragma unroll 1
    for (int t = 0; t < 2; t++) {
      const int slot = w2 + t;
      if (slot >= kNT / 32) break;
      const int eb = slot * 32;
#pragma unroll 1
      for (int ht = 0; ht < 2; ht++) {
        const int mb = eb + ht * 16;
        // node ids for the 4 edges this lane's acc column covers (issued early)
        int nid[4];
#pragma unroll
        for (int reg = 0; reg < 4; reg++) nid[reg] = nidx[mb + q * 4 + reg];
        // ---- layer A ----
        const float* arow = nhots + (size_t)(mb + p) * kR;
        s8v ah[2], al[2];
#pragma unroll
        for (int ks = 0; ks < 2; ks++) {
          const float4 xa = *(const float4*)(arow + ks * 32 + q8);
          const float4 xb = *(const float4*)(arow + ks * 32 + q8 + 4);
          split8(xa, xb, ah[ks], al[ks]);
        }
        f32x4 acc[4];
#pragma unroll
        for (int nt = 0; nt < 4; nt++) {
          acc[nt] = (f32x4)0.f;
#pragma unroll
          for (int ks = 0; ks < 2; ks++) {
            acc[nt] = __builtin_amdgcn_mfma_f32_16x16x32_bf16(ah[ks], Bh[nt][ks], acc[nt], 0, 0, 0);
            acc[nt] = __builtin_amdgcn_mfma_f32_16x16x32_bf16(ah[ks], Bl[nt][ks], acc[nt], 0, 0, 0);
            acc[nt] = __builtin_amdgcn_mfma_f32_16x16x32_bf16(al[ks], Bh[nt][ks], acc[nt], 0, 0, 0);
          }
        }
#pragma unroll
        for (int nt = 0; nt < 4; nt++)
#pragma unroll
          for (int reg = 0; reg < 4; reg++)
            sHf[wave][q * 4 + reg][nt * 16 + p] = fmaxf(acc[nt][reg] + bav[nt], 0.f);
        // ---- layer B + softmax (same wave; compiler inserts lgkmcnt) ----
        const float* hr = &sHf[wave][p][0];
        s8v hh[2], hl[2];
#pragma unroll
        for (int ks = 0; ks < 2; ks++) {
          const float4 xa = *(const float4*)(hr + ks * 32 + q8);
          const float4 xb = *(const float4*)(hr + ks * 32 + q8 + 4);
          split8(xa, xb, hh[ks], hl[ks]);
        }
        f32x4 accB = (f32x4)0.f;
#pragma unroll
        for (int ks = 0; ks < 2; ks++) {
          accB = __builtin_amdgcn_mfma_f32_16x16x32_bf16(hh[ks], Bbh[ks], accB, 0, 0, 0);
          accB = __builtin_amdgcn_mfma_f32_16x16x32_bf16(hh[ks], Bbl[ks], accB, 0, 0, 0);
          accB = __builtin_amdgcn_mfma_f32_16x16x32_bf16(hl[ks], Bbh[ks], accB, 0, 0, 0);
        }
#pragma unroll
        for (int reg = 0; reg < 4; reg++) {
          const float v = accB[reg] + bbv;
          float m = v;
#pragma unroll
          for (int d = 1; d < 16; d <<= 1) m = fmaxf(m, __shfl_xor(m, d));
          const float e = __expf(v - m);
          float sum = e;
#pragma unroll
          for (int d = 1; d < 16; d <<= 1) sum += __shfl_xor(sum, d);
          const float lv = e / sum;
          lato[(size_t)(mb + q * 4 + reg) * kRP + p] = lv;
          // fused per-node partial: 16 lanes of a q-group hit one 64B line
          atomicAdd(&part[(size_t)nid[reg] * kRP + p], lv);
        }
      }
    }
  }
}

// ---------- tots: sum of k=0 column of C1 / R2 (segment 0 aggregate) ----------
__global__ void __launch_bounds__(256)
k_tots(const float* __restrict__ C1, const float* __restrict__ R2,
       float* __restrict__ tots) {
  __shared__ float s0[4], s1[4];
  const int tid = threadIdx.x, wave = tid >> 6, lane = tid & 63;
  float a = 0.f, b = 0.f;
  for (int i = blockIdx.x * 256 + tid; i < kN; i += gridDim.x * 256) {
    a += C1[(size_t)i * kRP];
    b += R2[(size_t)i * kRP];
  }
#pragma unroll
  for (int d = 1; d < 64; d <<= 1) { a += __shfl_xor(a, d); b += __shfl_xor(b, d); }
  if (lane == 0) { s0[wave] = a; s1[wave] = b; }
  __syncthreads();
  if (tid == 0) {
    atomicAdd(&tots[0], s0[0] + s0[1] + s0[2] + s0[3]);
    atomicAdd(&tots[1], s1[0] + s1[1] + s1[2] + s1[3]);
  }
}

// ---------- csinv/rsinv via divisor enumeration ----------
__global__ void __launch_bounds__(256)
k_norms(const float* __restrict__ C1, const float* __restrict__ R2,
        const float* __restrict__ tots,
        float* __restrict__ csinv, float* __restrict__ rsinv) {
  const int m = blockIdx.x * 256 + threadIdx.x;
  if (m < kNRP) {
    float cs = (m == 0) ? tots[0] : 0.f;
    float rs = (m == 0) ? tots[1] : 0.f;
#pragma unroll
    for (int k = 1; k < kRP; k++) {
      if (m % k == 0) {
        const int q = m / k;
        if (q < kN) { cs += C1[q * kRP + k]; rs += R2[q * kRP + k]; }
      }
    }
    csinv[m] = (cs != 0.f) ? 1.f / cs : 0.f;
    rsinv[m] = (rs != 0.f) ? 1.f / rs : 0.f;
  }
}

// ---------- G build: G8[o][lane][j] bf16 = csinv[o*k]*wt1[o*k][c] ----------
__global__ void __launch_bounds__(256)
k_gbuild(const float* __restrict__ wt1, const float* __restrict__ csinv,
         unsigned* __restrict__ G8u) {
  __shared__ float sT[16][33];
  const int o = blockIdx.x;
  const int tid = threadIdx.x;
#pragma unroll
  for (int half = 0; half < 2; half++) {
    const int e = half * 256 + tid;
    const int k = e >> 5, c = e & 31;
    const int idx = o * k;
    sT[k][c] = csinv[idx] * wt1[(size_t)idx * kE + c];
  }
  __syncthreads();
  const int l = tid >> 2;
  const int c = l >> 1, kh = l & 1;
  const int j0 = (2 * tid) & 7;
  const int k0 = kh * 8 + j0, k1 = k0 + 1;
  const unsigned lo = (unsigned short)f2bf(sT[k0][c]);
  const unsigned hi = (unsigned short)f2bf(sT[k1][c]);
  G8u[(size_t)o * 256 + tid] = lo | (hi << 16);
}

// ---------- layer-1 gather via G: 16 B/lane/edge, batch-8 pipelined ----------
// One node per wave; edges are independent -> load up to 8 eo entries, then
// issue all 8 dependent gathers together (2 memory rounds per batch instead
// of 1 per edge). Mask m is wave-uniform (s is wave-uniform) -> cheap skips.
__global__ void __launch_bounds__(256)
k_layer1g(const int* __restrict__ rowptr, const int2* __restrict__ eo,
          const float* __restrict__ lat1, const uint4* __restrict__ G8,
          const float* __restrict__ bias1, float* __restrict__ h) {
  const int tid = threadIdx.x;
  const int wave = tid >> 6, lane = tid & 63;
  const int c = lane >> 1, kh = lane & 1;
  const float b1 = bias1[c];
  for (int s = blockIdx.x * 4 + wave; s < kN; s += gridDim.x * 4) {
    float acc = 0.f;
    const int beg = rowptr[s], end = rowptr[s + 1];
    for (int j0 = beg; j0 < end; j0 += 8) {
      const int m = end - j0;          // wave-uniform
      int2 E[8];
#pragma unroll
      for (int u = 0; u < 8; u++) if (u < m) E[u] = eo[j0 + u];
      uint4 g[8]; float4 la[8], lb[8];
#pragma unroll
      for (int u = 0; u < 8; u++) if (u < m) {
        g[u]  = G8[(size_t)E[u].y * 64 + lane];
        la[u] = *(const float4*)(lat1 + (size_t)E[u].x * kRP + kh * 8);
        lb[u] = *(const float4*)(lat1 + (size_t)E[u].x * kRP + kh * 8 + 4);
      }
#pragma unroll
      for (int u = 0; u < 8; u++) if (u < m) {
        acc = fmaf(la[u].x, bflo(g[u].x), acc); acc = fmaf(la[u].y, bfhi(g[u].x), acc);
        acc = fmaf(la[u].z, bflo(g[u].y), acc); acc = fmaf(la[u].w, bfhi(g[u].y), acc);
        acc = fmaf(lb[u].x, bflo(g[u].z), acc); acc = fmaf(lb[u].y, bfhi(g[u].z), acc);
        acc = fmaf(lb[u].z, bflo(g[u].w), acc); acc = fmaf(lb[u].w, bfhi(g[u].w), acc);
      }
    }
    acc += __shfl_xor(acc, 1);
    if (kh == 0) h[(size_t)s * kE + c] = fmaxf(acc + b1, 0.f);
  }
}

// ---------- per-s walk -> Ub[s][k-1][c] bf16; batch-8 pipelined ----------
__global__ void __launch_bounds__(256)
k_u(const int* __restrict__ rowptr, const int2* __restrict__ eo,
    const float* __restrict__ lat2, const float* __restrict__ rsinv,
    const float* __restrict__ h, short* __restrict__ Ub,
    float* __restrict__ pblk) {
  __shared__ float sacc[kE];
  const int tid = threadIdx.x;
  const int wave = tid >> 6, lane = tid & 63;
  const int c = lane & 31, half = lane >> 5;
  if (tid < kE) sacc[tid] = 0.f;
  __syncthreads();
  float hpart = 0.f;
  for (int s = blockIdx.x * 4 + wave; s < kN; s += gridDim.x * 4) {
    float u[8];
#pragma unroll
    for (int kk = 0; kk < 8; kk++) u[kk] = 0.f;
    const int beg = rowptr[s], end = rowptr[s + 1];
    for (int j0 = beg; j0 < end; j0 += 8) {
      const int m = end - j0;          // wave-uniform
      int2 E[8];
#pragma unroll
      for (int uu = 0; uu < 8; uu++) if (uu < m) E[uu] = eo[j0 + uu];
      float hv[8]; float4 la[8], lb[8];
#pragma unroll
      for (int uu = 0; uu < 8; uu++) if (uu < m) {
        hv[uu] = h[(size_t)E[uu].y * kE + c];
        const float4* lp = (const float4*)(lat2 + (size_t)E[uu].x * kRP) + half * 2;
        la[uu] = lp[0]; lb[uu] = lp[1];
      }
#pragma unroll
      for (int uu = 0; uu < 8; uu++) if (uu < m) {
        const float lv[8] = {la[uu].x, la[uu].y, la[uu].z, la[uu].w,
                             lb[uu].x, lb[uu].y, lb[uu].z, lb[uu].w};
#pragma unroll
        for (int kk = 0; kk < 8; kk++) u[kk] = fmaf(lv[kk], hv[uu], u[kk]);
      }
    }
    if (half == 0) hpart += u[0];
#pragma unroll
    for (int kk = 0; kk < 8; kk++) {
      const int k = half * 8 + kk;
      if (k >= 1)
        Ub[((size_t)s * 15 + (k - 1)) * kE + c] = f2bf(u[kk] * rsinv[s * k]);
    }
  }
  atomicAdd(&sacc[c], hpart);
  __syncthreads();
  if (tid < kE) pblk[(size_t)blockIdx.x * kE + tid] = sacc[tid];
}

// ---------- reduce per-block hrow0 partials ----------
__global__ void __launch_bounds__(256)
k_hred(const float* __restrict__ pblk, int nblk, float* __restrict__ hrow0) {
  __shared__ float sacc[kE];
  const int tid = threadIdx.x;
  if (tid < kE) sacc[tid] = 0.f;
  __syncthreads();
  const int total = nblk * kE;
  float r = 0.f;
  for (int i = blockIdx.x * 256 + tid; i < total; i += gridDim.x * 256)
    r += pblk[i];
  atomicAdd(&sacc[tid & 31], r);
  __syncthreads();
  if (tid < kE) atomicAdd(&hrow0[tid], sacc[tid]);
}

// ---------- dense H2[n][r][c] (bf16) via divisor gather, hoisted n%k ----------
// m = r*50000 + n; m%k==0 <=> n%k == (k - (r*50000)%k)%k (const);
// s = m/k < kN <=> k > r.
__global__ void __launch_bounds__(256)
k_h2(const short* __restrict__ Ub, const float* __restrict__ hrow0,
     const float* __restrict__ rsinv, short* __restrict__ H2) {
  const int tid = threadIdx.x;
  const int g = tid >> 5, c = tid & 31;
  const int n = blockIdx.x * 8 + g;          // grid = kN/8 exact
  const float rs0 = rsinv[0];
  int nm[16];
  nm[0] = 0; nm[1] = 0;
#pragma unroll
  for (int k = 2; k < kRP; k++) nm[k] = n % k;   // magic-mul per const k
#pragma unroll
  for (int r = 0; r < kRP; r++) {
    float row = 0.f;
    if (r == 0 && n == 0) row = hrow0[c] * rs0;
#pragma unroll
    for (int k = r + 1; k < kRP; k++) {
      const int target = (k - (r * 50000) % k) % k;   // compile-time const
      if (nm[k] == target) {
        const int s = (r * 50000 + n) / k;            // magic-div per const k
        row += bf2f(Ub[((size_t)s * 15 + (k - 1)) * kE + c]);
      }
    }
    H2[((size_t)n * kRP + r) * kE + c] = f2bf(row);
  }
}

// ---------- out = H2[N,512]bf16 @ W2[512,32] (split hi/lo) + bias2 ----------
__global__ void __launch_bounds__(256)
k_einsum(const short* __restrict__ H2, const float* __restrict__ W2,
         const float* __restrict__ bias2, float* __restrict__ out) {
  __shared__ short sBWh[16 * 2 * 64 * 8];    // 32 KB
  __shared__ short sBWl[16 * 2 * 64 * 8];    // 32 KB
  const int tid = threadIdx.x;
  for (int i = tid; i < 16384; i += 256) {
    const int j = i & 7, ln = (i >> 3) & 63, nt = (i >> 9) & 1, ks = i >> 10;
    const int pp = ln & 15, qq8 = (ln >> 4) * 8;
    const float v = W2[(ks * 32 + qq8 + j) * 32 + nt * 16 + pp];
    const short h = f2bf(v);
    sBWh[i] = h;
    sBWl[i] = f2bf(v - bf2f(h));
  }
  __syncthreads();
  const int wave = tid >> 6, lane = tid & 63;
  const int p = lane & 15, q = lane >> 4, q8 = q * 8;
  const float bias0 = bias2[p], bias1v = bias2[16 + p];
  for (int tile = blockIdx.x * 4 + wave; tile < kN / 16; tile += gridDim.x * 4) {
    const int mb = tile * 16;
    f32x4 acc0 = (f32x4)0.f, acc1 = (f32x4)0.f;
    const short* arow = H2 + (size_t)(mb + p) * 512 + q8;
#pragma unroll
    for (int ks = 0; ks < 16; ks++) {
      const s8v a   = *(const s8v*)(arow + ks * 32);
      const s8v b0h = *(const s8v*)(sBWh + ((ks * 2 + 0) * 64 + lane) * 8);
      const s8v b0l = *(const s8v*)(sBWl + ((ks * 2 + 0) * 64 + lane) * 8);
      const s8v b1h = *(const s8v*)(sBWh + ((ks * 2 + 1) * 64 + lane) * 8);
      const s8v b1l = *(const s8v*)(sBWl + ((ks * 2 + 1) * 64 + lane) * 8);
      acc0 = __builtin_amdgcn_mfma_f32_16x16x32_bf16(a, b0h, acc0, 0, 0, 0);
      acc0 = __builtin_amdgcn_mfma_f32_16x16x32_bf16(a, b0l, acc0, 0, 0, 0);
      acc1 = __builtin_amdgcn_mfma_f32_16x16x32_bf16(a, b1h, acc1, 0, 0, 0);
      acc1 = __builtin_amdgcn_mfma_f32_16x16x32_bf16(a, b1l, acc1, 0, 0, 0);
    }
#pragma unroll
    for (int reg = 0; reg < 4; reg++) {
      const int n = mb + q * 4 + reg;
      out[(size_t)n * kC + p]      = acc0[reg] + bias0;
      out[(size_t)n * kC + 16 + p] = acc1[reg] + bias1v;
    }
  }
}

// ---------- host ----------
extern "C" void kernel_launch(void* const* d_in, const int* in_sizes, int n_in,
                              void* d_out, int out_size, void* d_ws, size_t ws_size,
                              hipStream_t stream) {
  (void)in_sizes; (void)n_in; (void)out_size; (void)ws_size;
  const int* s_idx = (const int*)d_in[0];
  const int* o_idx = (const int*)d_in[1];
  const float* nhots = (const float*)d_in[2];
  const float* W1a = (const float*)d_in[3]; const float* b1a = (const float*)d_in[4];
  const float* W1b = (const float*)d_in[5]; const float* b1b = (const float*)d_in[6];
  const float* W2a = (const float*)d_in[7]; const float* b2a = (const float*)d_in[8];
  const float* W2b = (const float*)d_in[9]; const float* b2b = (const float*)d_in[10];
  const float* wt1 = (const float*)d_in[11]; const float* wt2 = (const float*)d_in[12];
  const float* bias1 = (const float*)d_in[13]; const float* bias2 = (const float*)d_in[14];

  char* ws = (char*)d_ws;
  size_t off = 0;
  auto alloc = [&](size_t bytes) -> char* {
    char* p = ws + off;
    off = (off + bytes + 255) & ~(size_t)255;
    return p;
  };
  char*  z0       = ws;                                    // zero region start
  int*   cnt_s    = (int*)  alloc((size_t)kN * 4);
  int*   cnt_o    = (int*)  alloc((size_t)kN * 4);
  int*   cursor_s = (int*)  alloc((size_t)kN * 4);
  int*   cursor_o = (int*)  alloc((size_t)kN * 4);
  float* tots     = (float*)alloc(8);
  float* hrow0    = (float*)alloc((size_t)kE * 4);
  float* C1       = (float*)alloc((size_t)kNRP * 4);       // 3.2 MB (zeroed: k_lat atomics)
  float* R2       = (float*)alloc((size_t)kNRP * 4);       // 3.2 MB (zeroed: k_lat atomics)
  const size_t zbytes = (size_t)((ws + off) - z0);         // ~7.2 MB
  short* Wf       = (short*)alloc((size_t)20480 * 2);      // 40 KB W frags
  int*   bs_s     = (int*)  alloc((size_t)kChunks * 4);
  int*   bs_o     = (int*)  alloc((size_t)kChunks * 4);
  int*   rowptr_s = (int*)  alloc((size_t)(kN + 1) * 4);
  int*   rowptr_o = (int*)  alloc((size_t)(kN + 1) * 4);
  float* pblk     = (float*)alloc((size_t)12500 * kE * 4); // 1.6 MB
  float* lat2     = (float*)alloc((size_t)kNT * kRP * 4);  // 19.2 MB
  int2*  eo_s     = (int2*) alloc((size_t)kNT * 8);        // 2.4 MB
  int*   e_o      = (int*)  alloc((size_t)kNT * 4);        // 1.2 MB
  float* csinv    = (float*)alloc((size_t)kNRP * 4);       // 3.2 MB
  float* rsinv    = (float*)alloc((size_t)kNRP * 4);       // 3.2 MB
  float* hbuf     = (float*)alloc((size_t)kN * kE * 4);    // 6.4 MB
  short* Ub       = (short*)alloc((size_t)kN * 15 * kE * 2);   // 48 MB
  char*  Greg     = alloc((size_t)kN * 1024);                  // 51.2 MB (G8, then H2)
  float* lat1     = (float*)Ub;        // alias: lat1 dead before k_u writes Ub
  unsigned* G8u   = (unsigned*)Greg;   // G dead before k_h2 writes H2
  short* H2       = (short*)Greg;
  // total ~144 MB (unchanged)

  hipMemsetAsync(z0, 0, zbytes, stream);

  const dim3 blk(256);
  const int gEdges = (kNT + 255) / 256;
  const int gLat = ((kNT / 32 + 1) / 2 + 3) / 4;   // 2 slots/wave, 4 waves/block

  k_count<<<gEdges, blk, 0, stream>>>(s_idx, o_idx, cnt_s, cnt_o);
  k_scan_p1<<<2 * kChunks, blk, 0, stream>>>(cnt_s, cnt_o, rowptr_s, rowptr_o, bs_s, bs_o);
  k_scan_p2<<<1, blk, 0, stream>>>(bs_s, bs_o);
  k_scan_p3<<<2 * kChunks, blk, 0, stream>>>(bs_s, bs_o, rowptr_s, rowptr_o);
  k_scatter2<<<gEdges, blk, 0, stream>>>(s_idx, o_idx, rowptr_s, cursor_s,
                                         rowptr_o, cursor_o, eo_s, e_o);
  k_wprep<<<1, blk, 0, stream>>>(W1a, W1b, W2a, W2b, Wf);
  k_lat<<<gLat, blk, 0, stream>>>(nhots, Wf, b1a, b1b, b2a, b2b,
                                  s_idx, o_idx, lat1, lat2, C1, R2);
  k_tots<<<64, blk, 0, stream>>>(C1, R2, tots);
  k_norms<<<(kNRP + 255) / 256, blk, 0, stream>>>(C1, R2, tots, csinv, rsinv);
  k_gbuild<<<kN, blk, 0, stream>>>(wt1, csinv, G8u);
  k_layer1g<<<12500, blk, 0, stream>>>(rowptr_s, eo_s, lat1, (const uint4*)G8u, bias1, hbuf);
  k_u<<<12500, blk, 0, stream>>>(rowptr_s, eo_s, lat2, rsinv, hbuf, Ub, pblk);
  k_hred<<<50, blk, 0, stream>>>(pblk, 12500, hrow0);
  k_h2<<<kN / 8, blk, 0, stream>>>(Ub, hrow0, rsinv, H2);
  k_einsum<<<782, blk, 0, stream>>>(H2, wt2, bias2, (float*)d_out);
}

// Round 4
// 556.236 us; speedup vs baseline: 1.1747x; 1.1747x over previous
//
#include <hip/hip_runtime.h>
#include <hip/hip_bf16.h>

#define DEV_INLINE __device__ __forceinline__

constexpr int kN   = 50000;
constexpr int kNT  = 300000;
constexpr int kR   = 64;
constexpr int kRP  = 16;
constexpr int kE   = 32;
constexpr int kC   = 32;
constexpr int kLW  = 64;
constexpr int kNRP = kN * kRP;     // 800000
constexpr int kChunks = (kN + 255) / 256;   // 196

typedef __attribute__((ext_vector_type(8))) short s8v;    // 8 bf16 (4 VGPRs)
typedef __attribute__((ext_vector_type(4))) float f32x4;  // MFMA acc

DEV_INLINE short f2bf(float f) {   // fp32 -> bf16 bits, RNE
  union { float f; unsigned u; } v; v.f = f;
  unsigned r = (v.u + 0x7fffu + ((v.u >> 16) & 1u)) >> 16;
  return (short)r;
}
DEV_INLINE float bf2f(short s) {
  union { unsigned u; float f; } v; v.u = ((unsigned)(unsigned short)s) << 16;
  return v.f;
}
DEV_INLINE float bflo(unsigned u) { union { unsigned x; float f; } a; a.x = u << 16;        return a.f; }
DEV_INLINE float bfhi(unsigned u) { union { unsigned x; float f; } a; a.x = u & 0xffff0000u; return a.f; }

union U4S8 { uint4 u; s8v s; };

// split 8 fp32 -> hi (truncated bf16) + lo (exact residual, truncated bf16)
DEV_INLINE void split8(const float4 A, const float4 B, s8v& hi, s8v& lo) {
  const float f[8] = {A.x, A.y, A.z, A.w, B.x, B.y, B.z, B.w};
  unsigned u[8], l[8];
#pragma unroll
  for (int i = 0; i < 8; i++) { union { float f; unsigned u; } c; c.f = f[i]; u[i] = c.u; }
#pragma unroll
  for (int i = 0; i < 8; i++) {
    union { unsigned u; float f; } t; t.u = u[i] & 0xffff0000u;
    union { float f; unsigned u; } c; c.f = f[i] - t.f; l[i] = c.u;
  }
  U4S8 H, L;
  H.u.x = (u[1] & 0xffff0000u) | (u[0] >> 16);
  H.u.y = (u[3] & 0xffff0000u) | (u[2] >> 16);
  H.u.z = (u[5] & 0xffff0000u) | (u[4] >> 16);
  H.u.w = (u[7] & 0xffff0000u) | (u[6] >> 16);
  L.u.x = (l[1] & 0xffff0000u) | (l[0] >> 16);
  L.u.y = (l[3] & 0xffff0000u) | (l[2] >> 16);
  L.u.z = (l[5] & 0xffff0000u) | (l[4] >> 16);
  L.u.w = (l[7] & 0xffff0000u) | (l[6] >> 16);
  hi = H.s; lo = L.s;
}

// ---------- K0: degree counts (s-side CSR only) ----------
__global__ void __launch_bounds__(256)
k_count(const int* __restrict__ s_idx, int* __restrict__ cnt_s) {
  const int e = blockIdx.x * 256 + threadIdx.x;
  if (e < kNT) atomicAdd(&cnt_s[s_idx[e]], 1);
}

// ---------- parallel scan, phase 1 ----------
__global__ void __launch_bounds__(256)
k_scan_p1(const int* __restrict__ cnt, int* __restrict__ rp, int* __restrict__ bs) {
  __shared__ int ws[4];
  const int tid = threadIdx.x, wave = tid >> 6, lane = tid & 63;
  const int i = blockIdx.x * 256 + tid;
  int v = (i < kN) ? cnt[i] : 0;
  int incl = v;
#pragma unroll
  for (int off = 1; off < 64; off <<= 1) {
    int tmp = __shfl_up(incl, off, 64);
    if (lane >= off) incl += tmp;
  }
  if (lane == 63) ws[wave] = incl;
  __syncthreads();
  int add = 0;
#pragma unroll
  for (int w = 0; w < 4; w++) if (w < wave) add += ws[w];
  incl += add;
  if (i < kN) rp[i + 1] = incl;
  if (tid == 255) bs[blockIdx.x] = incl;
}

// ---------- phase 2 ----------
__global__ void __launch_bounds__(256)
k_scan_p2(int* __restrict__ bs) {
  __shared__ int ws[4];
  const int tid = threadIdx.x, wave = tid >> 6, lane = tid & 63;
  const int v = (tid < kChunks) ? bs[tid] : 0;
  int incl = v;
#pragma unroll
  for (int off = 1; off < 64; off <<= 1) {
    int tmp = __shfl_up(incl, off, 64);
    if (lane >= off) incl += tmp;
  }
  if (lane == 63) ws[wave] = incl;
  __syncthreads();
  int add = 0;
#pragma unroll
  for (int w = 0; w < 4; w++) if (w < wave) add += ws[w];
  incl += add;
  if (tid < kChunks) bs[tid] = incl - v;
}

// ---------- phase 3 ----------
__global__ void __launch_bounds__(256)
k_scan_p3(const int* __restrict__ bs, int* __restrict__ rp) {
  const int i = blockIdx.x * 256 + threadIdx.x;
  if (i < kN) rp[i + 1] += bs[blockIdx.x];
  if (blockIdx.x == 0 && threadIdx.x == 0) rp[0] = 0;
}

// ---------- scatter: o per CSR slot + edge->slot map ----------
__global__ void __launch_bounds__(256)
k_scatter(const int* __restrict__ s_idx, const int* __restrict__ o_idx,
          const int* __restrict__ rowptr, int* __restrict__ cursor,
          int* __restrict__ o_csr, int* __restrict__ sslot) {
  const int e = blockIdx.x * 256 + threadIdx.x;
  if (e < kNT) {
    const int s = s_idx[e];
    const int ps = atomicAdd(&cursor[s], 1);
    const int slot = rowptr[s] + ps;
    o_csr[slot] = o_idx[e];
    sslot[e] = slot;
  }
}

// ---------- W-frag prep: split-bf16 fragments in B-layout, once ----------
__global__ void __launch_bounds__(256)
k_wprep(const float* __restrict__ W1a, const float* __restrict__ W1b,
        const float* __restrict__ W2a, const float* __restrict__ W2b,
        short* __restrict__ Wf) {
  const int tid = threadIdx.x;
  for (int i = tid; i < 8192; i += 256) {
    const int j = i & 7, lane = (i >> 3) & 63, ks = (i >> 9) & 1,
              nt = (i >> 10) & 3, mlp = i >> 12;
    const int p = lane & 15, q8 = (lane >> 4) * 8;
    const float* Wa = mlp ? W2a : W1a;
    const float v = Wa[(ks * 32 + q8 + j) * kLW + nt * 16 + p];
    union { float f; unsigned u; } c; c.f = v;
    const short h = (short)(c.u >> 16);
    Wf[i] = h;
    Wf[8192 + i] = f2bf(v - bf2f(h));
  }
  for (int i = tid; i < 2048; i += 256) {
    const int j = i & 7, lane = (i >> 3) & 63, ks = (i >> 9) & 1, mlp = i >> 10;
    const int p = lane & 15, q8 = (lane >> 4) * 8;
    const float* Wb = mlp ? W2b : W1b;
    const float v = Wb[(ks * 32 + q8 + j) * kRP + p];
    union { float f; unsigned u; } c; c.f = v;
    const short h = (short)(c.u >> 16);
    Wf[16384 + i] = h;
    Wf[18432 + i] = f2bf(v - bf2f(h));
  }
}

// ---------- K1: BOTH edge MLPs + softmax via split-bf16 MFMA ----------
// Round-1 structure (mlp-outer, 2 slots/wave). lat1/lat2 are written in
// s-CSR SLOT order (sslot[e]) so the downstream walk kernels read them
// contiguously with index-independent addresses. Fused per-node partials
// C1[o][k] / R2[s][k] via atomics.
__global__ void __launch_bounds__(256)
k_lat(const float* __restrict__ nhots, const short* __restrict__ Wf,
      const float* __restrict__ b1a, const float* __restrict__ b1b,
      const float* __restrict__ b2a, const float* __restrict__ b2b,
      const int* __restrict__ s_idx, const int* __restrict__ o_idx,
      const int* __restrict__ sslot,
      float* __restrict__ lat1o, float* __restrict__ lat2o,
      float* __restrict__ C1, float* __restrict__ R2) {
  __shared__ float sHf[4][16][68];       // 17.4 KB, per-wave tile
  const int tid = threadIdx.x;
  const int wave = tid >> 6, lane = tid & 63;
  const int p = lane & 15, q = lane >> 4, q8 = (lane >> 4) * 8;

  const uint4* BaH4 = (const uint4*)(Wf);
  const uint4* BaL4 = (const uint4*)(Wf + 8192);
  const uint4* BbH4 = (const uint4*)(Wf + 16384);
  const uint4* BbL4 = (const uint4*)(Wf + 18432);

  const int w2 = (blockIdx.x * 4 + wave) * 2;   // first of 2 tile slots

#pragma unroll 1
  for (int mlp = 0; mlp < 2; mlp++) {
    s8v Bh[4][2], Bl[4][2], Bbh[2], Bbl[2];
#pragma unroll
    for (int nt = 0; nt < 4; nt++)
#pragma unroll
      for (int ks = 0; ks < 2; ks++) {
        U4S8 a, b;
        a.u = BaH4[((mlp * 4 + nt) * 2 + ks) * 64 + lane];
        b.u = BaL4[((mlp * 4 + nt) * 2 + ks) * 64 + lane];
        Bh[nt][ks] = a.s; Bl[nt][ks] = b.s;
      }
#pragma unroll
    for (int ks = 0; ks < 2; ks++) {
      U4S8 a, b;
      a.u = BbH4[(mlp * 2 + ks) * 64 + lane];
      b.u = BbL4[(mlp * 2 + ks) * 64 + lane];
      Bbh[ks] = a.s; Bbl[ks] = b.s;
    }
    const float* bA = mlp ? b2a : b1a;
    const float* bB = mlp ? b2b : b1b;
    float bav[4];
#pragma unroll
    for (int nt = 0; nt < 4; nt++) bav[nt] = bA[nt * 16 + p];
    const float bbv = bB[p];
    float* lato = mlp ? lat2o : lat1o;
    const int* nidx = mlp ? s_idx : o_idx;   // lat2 -> R2[s], lat1 -> C1[o]
    float* part = mlp ? R2 : C1;

#pragma unroll 1
    for (int t = 0; t < 2; t++) {
      const int slot = w2 + t;
      if (slot >= kNT / 32) break;
      const int eb = slot * 32;
#pragma unroll 1
      for (int ht = 0; ht < 2; ht++) {
        const int mb = eb + ht * 16;
        // node ids + CSR slots for the 4 edges this lane covers (issued early)
        int nid[4], sl[4];
#pragma unroll
        for (int reg = 0; reg < 4; reg++) {
          const int m = mb + q * 4 + reg;
          nid[reg] = nidx[m];
          sl[reg]  = sslot[m];
        }
        // ---- layer A ----
        const float* arow = nhots + (size_t)(mb + p) * kR;
        s8v ah[2], al[2];
#pragma unroll
        for (int ks = 0; ks < 2; ks++) {
          const float4 xa = *(const float4*)(arow + ks * 32 + q8);
          const float4 xb = *(const float4*)(arow + ks * 32 + q8 + 4);
          split8(xa, xb, ah[ks], al[ks]);
        }
        f32x4 acc[4];
#pragma unroll
        for (int nt = 0; nt < 4; nt++) {
          acc[nt] = (f32x4)0.f;
#pragma unroll
          for (int ks = 0; ks < 2; ks++) {
            acc[nt] = __builtin_amdgcn_mfma_f32_16x16x32_bf16(ah[ks], Bh[nt][ks], acc[nt], 0, 0, 0);
            acc[nt] = __builtin_amdgcn_mfma_f32_16x16x32_bf16(ah[ks], Bl[nt][ks], acc[nt], 0, 0, 0);
            acc[nt] = __builtin_amdgcn_mfma_f32_16x16x32_bf16(al[ks], Bh[nt][ks], acc[nt], 0, 0, 0);
          }
        }
#pragma unroll
        for (int nt = 0; nt < 4; nt++)
#pragma unroll
          for (int reg = 0; reg < 4; reg++)
            sHf[wave][q * 4 + reg][nt * 16 + p] = fmaxf(acc[nt][reg] + bav[nt], 0.f);
        // ---- layer B + softmax ----
        const float* hr = &sHf[wave][p][0];
        s8v hh[2], hl[2];
#pragma unroll
        for (int ks = 0; ks < 2; ks++) {
          const float4 xa = *(const float4*)(hr + ks * 32 + q8);
          const float4 xb = *(const float4*)(hr + ks * 32 + q8 + 4);
          split8(xa, xb, hh[ks], hl[ks]);
        }
        f32x4 accB = (f32x4)0.f;
#pragma unroll
        for (int ks = 0; ks < 2; ks++) {
          accB = __builtin_amdgcn_mfma_f32_16x16x32_bf16(hh[ks], Bbh[ks], accB, 0, 0, 0);
          accB = __builtin_amdgcn_mfma_f32_16x16x32_bf16(hh[ks], Bbl[ks], accB, 0, 0, 0);
          accB = __builtin_amdgcn_mfma_f32_16x16x32_bf16(hl[ks], Bbh[ks], accB, 0, 0, 0);
        }
#pragma unroll
        for (int reg = 0; reg < 4; reg++) {
          const float v = accB[reg] + bbv;
          float m = v;
#pragma unroll
          for (int d = 1; d < 16; d <<= 1) m = fmaxf(m, __shfl_xor(m, d));
          const float e = __expf(v - m);
          float sum = e;
#pragma unroll
          for (int d = 1; d < 16; d <<= 1) sum += __shfl_xor(sum, d);
          const float lv = e / sum;
          lato[(size_t)sl[reg] * kRP + p] = lv;   // CSR-slot order
          atomicAdd(&part[(size_t)nid[reg] * kRP + p], lv);
        }
      }
    }
  }
}

// ---------- tots: sum of k=0 column of C1 / R2 ----------
__global__ void __launch_bounds__(256)
k_tots(const float* __restrict__ C1, const float* __restrict__ R2,
       float* __restrict__ tots) {
  __shared__ float s0[4], s1[4];
  const int tid = threadIdx.x, wave = tid >> 6, lane = tid & 63;
  float a = 0.f, b = 0.f;
  for (int i = blockIdx.x * 256 + tid; i < kN; i += gridDim.x * 256) {
    a += C1[(size_t)i * kRP];
    b += R2[(size_t)i * kRP];
  }
#pragma unroll
  for (int d = 1; d < 64; d <<= 1) { a += __shfl_xor(a, d); b += __shfl_xor(b, d); }
  if (lane == 0) { s0[wave] = a; s1[wave] = b; }
  __syncthreads();
  if (tid == 0) {
    atomicAdd(&tots[0], s0[0] + s0[1] + s0[2] + s0[3]);
    atomicAdd(&tots[1], s1[0] + s1[1] + s1[2] + s1[3]);
  }
}

// ---------- csinv/rsinv via divisor enumeration ----------
__global__ void __launch_bounds__(256)
k_norms(const float* __restrict__ C1, const float* __restrict__ R2,
        const float* __restrict__ tots,
        float* __restrict__ csinv, float* __restrict__ rsinv) {
  const int m = blockIdx.x * 256 + threadIdx.x;
  if (m < kNRP) {
    float cs = (m == 0) ? tots[0] : 0.f;
    float rs = (m == 0) ? tots[1] : 0.f;
#pragma unroll
    for (int k = 1; k < kRP; k++) {
      if (m % k == 0) {
        const int q = m / k;
        if (q < kN) { cs += C1[q * kRP + k]; rs += R2[q * kRP + k]; }
      }
    }
    csinv[m] = (cs != 0.f) ? 1.f / cs : 0.f;
    rsinv[m] = (rs != 0.f) ? 1.f / rs : 0.f;
  }
}

// ---------- G build: G8[o][lane][j] bf16 = csinv[o*k]*wt1[o*k][c] ----------
__global__ void __launch_bounds__(256)
k_gbuild(const float* __restrict__ wt1, const float* __restrict__ csinv,
         unsigned* __restrict__ G8u) {
  __shared__ float sT[16][33];
  const int o = blockIdx.x;
  const int tid = threadIdx.x;
#pragma unroll
  for (int half = 0; half < 2; half++) {
    const int e = half * 256 + tid;
    const int k = e >> 5, c = e & 31;
    const int idx = o * k;
    sT[k][c] = csinv[idx] * wt1[(size_t)idx * kE + c];
  }
  __syncthreads();
  const int l = tid >> 2;
  const int c = l >> 1, kh = l & 1;
  const int j0 = (2 * tid) & 7;
  const int k0 = kh * 8 + j0, k1 = k0 + 1;
  const unsigned lo = (unsigned short)f2bf(sT[k0][c]);
  const unsigned hi = (unsigned short)f2bf(sT[k1][c]);
  G8u[(size_t)o * 256 + tid] = lo | (hi << 16);
}

// ---------- layer-1: contiguous lat1 + depth-1 pipelined G8 gather ----------
// lat1 is in CSR-slot order: address depends only on j (off the latency
// chain). o fetched 2 ahead; G8 gather + lat row staged 1 ahead, rotated
// through NAMED scalars (never init'd from pending loads).
__global__ void __launch_bounds__(256)
k_layer1g(const int* __restrict__ rowptr, const int* __restrict__ o_csr,
          const float* __restrict__ lat1, const uint4* __restrict__ G8,
          const float* __restrict__ bias1, float* __restrict__ h) {
  const int tid = threadIdx.x;
  const int wave = tid >> 6, lane = tid & 63;
  const int c = lane >> 1, kh = lane & 1;
  const float b1 = bias1[c];
  for (int s = blockIdx.x * 4 + wave; s < kN; s += gridDim.x * 4) {
    const int beg = rowptr[s], end = rowptr[s + 1];
    float acc = 0.f;
    int o1 = 0;
    uint4 g0 = (uint4){0, 0, 0, 0};
    float4 la0 = (float4){0.f, 0.f, 0.f, 0.f}, lb0 = la0;
    if (beg < end) {
      const int o0 = o_csr[beg];
      if (beg + 1 < end) o1 = o_csr[beg + 1];
      g0  = G8[(size_t)o0 * 64 + lane];
      la0 = *(const float4*)(lat1 + (size_t)beg * kRP + kh * 8);
      lb0 = *(const float4*)(lat1 + (size_t)beg * kRP + kh * 8 + 4);
    }
    for (int j = beg; j < end; j++) {
      int on = 0;
      uint4 gn = (uint4){0, 0, 0, 0};
      float4 lan = (float4){0.f, 0.f, 0.f, 0.f}, lbn = lan;
      if (j + 2 < end) on = o_csr[j + 2];
      if (j + 1 < end) {
        gn  = G8[(size_t)o1 * 64 + lane];
        lan = *(const float4*)(lat1 + (size_t)(j + 1) * kRP + kh * 8);
        lbn = *(const float4*)(lat1 + (size_t)(j + 1) * kRP + kh * 8 + 4);
      }
      acc = fmaf(la0.x, bflo(g0.x), acc); acc = fmaf(la0.y, bfhi(g0.x), acc);
      acc = fmaf(la0.z, bflo(g0.y), acc); acc = fmaf(la0.w, bfhi(g0.y), acc);
      acc = fmaf(lb0.x, bflo(g0.z), acc); acc = fmaf(lb0.y, bfhi(g0.z), acc);
      acc = fmaf(lb0.z, bflo(g0.w), acc); acc = fmaf(lb0.w, bfhi(g0.w), acc);
      o1 = on; g0 = gn; la0 = lan; lb0 = lbn;
    }
    acc += __shfl_xor(acc, 1);
    if (kh == 0) h[(size_t)s * kE + c] = fmaxf(acc + b1, 0.f);
  }
}

// ---------- per-s walk -> Ub; contiguous lat2 + depth-1 pipelined h gather ----------
__global__ void __launch_bounds__(256)
k_u(const int* __restrict__ rowptr, const int* __restrict__ o_csr,
    const float* __restrict__ lat2, const float* __restrict__ rsinv,
    const float* __restrict__ h, short* __restrict__ Ub,
    float* __restrict__ pblk) {
  __shared__ float sacc[kE];
  const int tid = threadIdx.x;
  const int wave = tid >> 6, lane = tid & 63;
  const int c = lane & 31, half = lane >> 5;
  if (tid < kE) sacc[tid] = 0.f;
  __syncthreads();
  float hpart = 0.f;
  for (int s = blockIdx.x * 4 + wave; s < kN; s += gridDim.x * 4) {
    float u[8];
#pragma unroll
    for (int kk = 0; kk < 8; kk++) u[kk] = 0.f;
    const int beg = rowptr[s], end = rowptr[s + 1];
    int o1 = 0;
    float hv0 = 0.f;
    float4 la0 = (float4){0.f, 0.f, 0.f, 0.f}, lb0 = la0;
    if (beg < end) {
      const int o0 = o_csr[beg];
      if (beg + 1 < end) o1 = o_csr[beg + 1];
      hv0 = h[(size_t)o0 * kE + c];
      const float4* lp = (const float4*)(lat2 + (size_t)beg * kRP) + half * 2;
      la0 = lp[0]; lb0 = lp[1];
    }
    for (int j = beg; j < end; j++) {
      int on = 0;
      float hvn = 0.f;
      float4 lan = (float4){0.f, 0.f, 0.f, 0.f}, lbn = lan;
      if (j + 2 < end) on = o_csr[j + 2];
      if (j + 1 < end) {
        hvn = h[(size_t)o1 * kE + c];
        const float4* lp = (const float4*)(lat2 + (size_t)(j + 1) * kRP) + half * 2;
        lan = lp[0]; lbn = lp[1];
      }
      u[0] = fmaf(la0.x, hv0, u[0]); u[1] = fmaf(la0.y, hv0, u[1]);
      u[2] = fmaf(la0.z, hv0, u[2]); u[3] = fmaf(la0.w, hv0, u[3]);
      u[4] = fmaf(lb0.x, hv0, u[4]); u[5] = fmaf(lb0.y, hv0, u[5]);
      u[6] = fmaf(lb0.z, hv0, u[6]); u[7] = fmaf(lb0.w, hv0, u[7]);
      o1 = on; hv0 = hvn; la0 = lan; lb0 = lbn;
    }
    if (half == 0) hpart += u[0];
#pragma unroll
    for (int kk = 0; kk < 8; kk++) {
      const int k = half * 8 + kk;
      if (k >= 1)
        Ub[((size_t)s * 15 + (k - 1)) * kE + c] = f2bf(u[kk] * rsinv[s * k]);
    }
  }
  atomicAdd(&sacc[c], hpart);
  __syncthreads();
  if (tid < kE) pblk[(size_t)blockIdx.x * kE + tid] = sacc[tid];
}

// ---------- reduce per-block hrow0 partials ----------
__global__ void __launch_bounds__(256)
k_hred(const float* __restrict__ pblk, int nblk, float* __restrict__ hrow0) {
  __shared__ float sacc[kE];
  const int tid = threadIdx.x;
  if (tid < kE) sacc[tid] = 0.f;
  __syncthreads();
  const int total = nblk * kE;
  float r = 0.f;
  for (int i = blockIdx.x * 256 + tid; i < total; i += gridDim.x * 256)
    r += pblk[i];
  atomicAdd(&sacc[tid & 31], r);
  __syncthreads();
  if (tid < kE) atomicAdd(&hrow0[tid], sacc[tid]);
}

// ---------- dense H2[n][r][c] (bf16) via divisor gather ----------
__global__ void __launch_bounds__(256)
k_h2(const short* __restrict__ Ub, const float* __restrict__ hrow0,
     const float* __restrict__ rsinv, short* __restrict__ H2) {
  const int tid = threadIdx.x;
  const int g = tid >> 5, c = tid & 31;
  const int n = blockIdx.x * 8 + g;          // grid = kN/8 exact
  const float rs0 = rsinv[0];
  int nm[16];
  nm[0] = 0; nm[1] = 0;
#pragma unroll
  for (int k = 2; k < kRP; k++) nm[k] = n % k;
#pragma unroll
  for (int r = 0; r < kRP; r++) {
    float row = 0.f;
    if (r == 0 && n == 0) row = hrow0[c] * rs0;
#pragma unroll
    for (int k = r + 1; k < kRP; k++) {
      const int target = (k - (r * 50000) % k) % k;
      if (nm[k] == target) {
        const int s = (r * 50000 + n) / k;
        row += bf2f(Ub[((size_t)s * 15 + (k - 1)) * kE + c]);
      }
    }
    H2[((size_t)n * kRP + r) * kE + c] = f2bf(row);
  }
}

// ---------- out = H2[N,512]bf16 @ W2[512,32] (split hi/lo) + bias2 ----------
__global__ void __launch_bounds__(256)
k_einsum(const short* __restrict__ H2, const float* __restrict__ W2,
         const float* __restrict__ bias2, float* __restrict__ out) {
  __shared__ short sBWh[16 * 2 * 64 * 8];    // 32 KB
  __shared__ short sBWl[16 * 2 * 64 * 8];    // 32 KB
  const int tid = threadIdx.x;
  for (int i = tid; i < 16384; i += 256) {
    const int j = i & 7, ln = (i >> 3) & 63, nt = (i >> 9) & 1, ks = i >> 10;
    const int pp = ln & 15, qq8 = (ln >> 4) * 8;
    const float v = W2[(ks * 32 + qq8 + j) * 32 + nt * 16 + pp];
    const short h = f2bf(v);
    sBWh[i] = h;
    sBWl[i] = f2bf(v - bf2f(h));
  }
  __syncthreads();
  const int wave = tid >> 6, lane = tid & 63;
  const int p = lane & 15, q = lane >> 4, q8 = q * 8;
  const float bias0 = bias2[p], bias1v = bias2[16 + p];
  for (int tile = blockIdx.x * 4 + wave; tile < kN / 16; tile += gridDim.x * 4) {
    const int mb = tile * 16;
    f32x4 acc0 = (f32x4)0.f, acc1 = (f32x4)0.f;
    const short* arow = H2 + (size_t)(mb + p) * 512 + q8;
#pragma unroll
    for (int ks = 0; ks < 16; ks++) {
      const s8v a   = *(const s8v*)(arow + ks * 32);
      const s8v b0h = *(const s8v*)(sBWh + ((ks * 2 + 0) * 64 + lane) * 8);
      const s8v b0l = *(const s8v*)(sBWl + ((ks * 2 + 0) * 64 + lane) * 8);
      const s8v b1h = *(const s8v*)(sBWh + ((ks * 2 + 1) * 64 + lane) * 8);
      const s8v b1l = *(const s8v*)(sBWl + ((ks * 2 + 1) * 64 + lane) * 8);
      acc0 = __builtin_amdgcn_mfma_f32_16x16x32_bf16(a, b0h, acc0, 0, 0, 0);
      acc0 = __builtin_amdgcn_mfma_f32_16x16x32_bf16(a, b0l, acc0, 0, 0, 0);
      acc1 = __builtin_amdgcn_mfma_f32_16x16x32_bf16(a, b1h, acc1, 0, 0, 0);
      acc1 = __builtin_amdgcn_mfma_f32_16x16x32_bf16(a, b1l, acc1, 0, 0, 0);
    }
#pragma unroll
    for (int reg = 0; reg < 4; reg++) {
      const int n = mb + q * 4 + reg;
      out[(size_t)n * kC + p]      = acc0[reg] + bias0;
      out[(size_t)n * kC + 16 + p] = acc1[reg] + bias1v;
    }
  }
}

// ---------- host ----------
extern "C" void kernel_launch(void* const* d_in, const int* in_sizes, int n_in,
                              void* d_out, int out_size, void* d_ws, size_t ws_size,
                              hipStream_t stream) {
  (void)in_sizes; (void)n_in; (void)out_size; (void)ws_size;
  const int* s_idx = (const int*)d_in[0];
  const int* o_idx = (const int*)d_in[1];
  const float* nhots = (const float*)d_in[2];
  const float* W1a = (const float*)d_in[3]; const float* b1a = (const float*)d_in[4];
  const float* W1b = (const float*)d_in[5]; const float* b1b = (const float*)d_in[6];
  const float* W2a = (const float*)d_in[7]; const float* b2a = (const float*)d_in[8];
  const float* W2b = (const float*)d_in[9]; const float* b2b = (const float*)d_in[10];
  const float* wt1 = (const float*)d_in[11]; const float* wt2 = (const float*)d_in[12];
  const float* bias1 = (const float*)d_in[13]; const float* bias2 = (const float*)d_in[14];

  char* ws = (char*)d_ws;
  size_t off = 0;
  auto alloc = [&](size_t bytes) -> char* {
    char* p = ws + off;
    off = (off + bytes + 255) & ~(size_t)255;
    return p;
  };
  char*  z0       = ws;                                    // zero region start
  int*   cnt_s    = (int*)  alloc((size_t)kN * 4);
  int*   cursor_s = (int*)  alloc((size_t)kN * 4);
  float* tots     = (float*)alloc(8);
  float* hrow0    = (float*)alloc((size_t)kE * 4);
  float* C1       = (float*)alloc((size_t)kNRP * 4);       // 3.2 MB
  float* R2       = (float*)alloc((size_t)kNRP * 4);       // 3.2 MB
  const size_t zbytes = (size_t)((ws + off) - z0);         // ~6.8 MB
  short* Wf       = (short*)alloc((size_t)20480 * 2);      // 40 KB W frags
  int*   bs_s     = (int*)  alloc((size_t)kChunks * 4);
  int*   rowptr_s = (int*)  alloc((size_t)(kN + 1) * 4);
  int*   pblk     = (int*)  nullptr;
  float* pblkf    = (float*)alloc((size_t)12500 * kE * 4); // 1.6 MB
  float* lat2     = (float*)alloc((size_t)kNT * kRP * 4);  // 19.2 MB (CSR-slot order)
  int*   o_csr    = (int*)  alloc((size_t)kNT * 4);        // 1.2 MB
  int*   sslot    = (int*)  alloc((size_t)kNT * 4);        // 1.2 MB
  float* csinv    = (float*)alloc((size_t)kNRP * 4);       // 3.2 MB
  float* rsinv    = (float*)alloc((size_t)kNRP * 4);       // 3.2 MB
  float* hbuf     = (float*)alloc((size_t)kN * kE * 4);    // 6.4 MB
  short* Ub       = (short*)alloc((size_t)kN * 15 * kE * 2);   // 48 MB
  char*  Greg     = alloc((size_t)kN * 1024);                  // 51.2 MB (G8, then H2)
  float* lat1     = (float*)Ub;        // alias: lat1 dead before k_u writes Ub
  unsigned* G8u   = (unsigned*)Greg;   // G dead before k_h2 writes H2
  short* H2       = (short*)Greg;
  (void)pblk;
  // total ~142 MB

  hipMemsetAsync(z0, 0, zbytes, stream);

  const dim3 blk(256);
  const int gEdges = (kNT + 255) / 256;
  const int gLat = ((kNT / 32 + 1) / 2 + 3) / 4;   // 2 slots/wave, 4 waves/block

  k_count<<<gEdges, blk, 0, stream>>>(s_idx, cnt_s);
  k_scan_p1<<<kChunks, blk, 0, stream>>>(cnt_s, rowptr_s, bs_s);
  k_scan_p2<<<1, blk, 0, stream>>>(bs_s);
  k_scan_p3<<<kChunks, blk, 0, stream>>>(bs_s, rowptr_s);
  k_scatter<<<gEdges, blk, 0, stream>>>(s_idx, o_idx, rowptr_s, cursor_s,
                                        o_csr, sslot);
  k_wprep<<<1, blk, 0, stream>>>(W1a, W1b, W2a, W2b, Wf);
  k_lat<<<gLat, blk, 0, stream>>>(nhots, Wf, b1a, b1b, b2a, b2b,
                                  s_idx, o_idx, sslot, lat1, lat2, C1, R2);
  k_tots<<<64, blk, 0, stream>>>(C1, R2, tots);
  k_norms<<<(kNRP + 255) / 256, blk, 0, stream>>>(C1, R2, tots, csinv, rsinv);
  k_gbuild<<<kN, blk, 0, stream>>>(wt1, csinv, G8u);
  k_layer1g<<<12500, blk, 0, stream>>>(rowptr_s, o_csr, lat1, (const uint4*)G8u, bias1, hbuf);
  k_u<<<12500, blk, 0, stream>>>(rowptr_s, o_csr, lat2, rsinv, hbuf, Ub, pblkf);
  k_hred<<<50, blk, 0, stream>>>(pblkf, 12500, hrow0);
  k_h2<<<kN / 8, blk, 0, stream>>>(Ub, hrow0, rsinv, H2);
  k_einsum<<<782, blk, 0, stream>>>(H2, wt2, bias2, (float*)d_out);
}